// Round 9
// baseline (516.166 us; speedup 1.0000x reference)
//
#include <hip/hip_runtime.h>
#include <hip/hip_bf16.h>

#define NQ     300
#define NH     8
#define HID    256
#define NLVL   4
#define NCELL  49
#define TOTAL  21760

typedef unsigned short ushort_t;
typedef __attribute__((ext_vector_type(8))) short short8;
typedef __attribute__((ext_vector_type(4))) float floatx4;

__device__ __forceinline__ float bfbits2f(ushort_t u) {
    union { unsigned int i; float f; } x;
    x.i = ((unsigned int)u) << 16;
    return x.f;
}
__device__ __forceinline__ ushort_t f2bfbits(float v) {
    __hip_bfloat16 h = __float2bfloat16(v);
    return *(ushort_t*)&h;
}
__device__ __forceinline__ void split_bf(float v, ushort_t& hi, ushort_t& lo) {
    __hip_bfloat16 h = __float2bfloat16(v);
    hi = *(ushort_t*)&h;
    float hv = __bfloat162float(h);
    __hip_bfloat16 l = __float2bfloat16(v - hv);
    lo = *(ushort_t*)&l;
}

// ---------------------------------------------------------------------------
// ROI helpers — bf16 memory variant
// ---------------------------------------------------------------------------
struct Box {
    float sx, sy, bw, bh, Wf;
    int W;
    const ushort_t* memb;
};

__device__ __forceinline__ void load_box(const float* __restrict__ refr,
                                         const ushort_t* __restrict__ mem16,
                                         int r, int lvl, int lane, Box& bx) {
    const int lvl_hw[4] = {128, 64, 32, 16};
    const int lvl_s[4]  = {0, 16384, 20480, 21504};
    const int b = r / NQ;
    bx.W  = lvl_hw[lvl];
    bx.Wf = (float)bx.W;
    const float* rp = refr + ((size_t)r * NLVL + lvl) * 6;
    float cx = rp[0], cy = rp[1];
    float dl = rp[2], dt = rp[3], dr = rp[4], db = rp[5];
    float x1 = fminf(fmaxf(cx - dl, 0.f), 1.f) * bx.Wf;
    float y1 = fminf(fmaxf(cy - dt, 0.f), 1.f) * bx.Wf;
    float x2 = fminf(fmaxf(cx + dr, 0.f), 1.f) * bx.Wf;
    float y2 = fminf(fmaxf(cy + db, 0.f), 1.f) * bx.Wf;
    bx.sx = x1 - 0.5f;
    bx.sy = y1 - 0.5f;
    bx.bw = (x2 - x1) * (1.f / 7.f);
    bx.bh = (y2 - y1) * (1.f / 7.f);
    bx.memb = mem16 + ((size_t)b * TOTAL + lvl_s[lvl]) * HID + lane * 4;
}

__device__ __forceinline__ void roi_cell(const Box& bx, int cell, float4& out) {
    const int ph = cell / 7, pw = cell % 7;
    float a0 = 0.f, a1 = 0.f, a2 = 0.f, a3 = 0.f;
#pragma unroll
    for (int sub = 0; sub < 4; ++sub) {
        const float tys = (float)ph + ((sub >> 1) + 0.5f) * 0.5f;
        const float txs = (float)pw + ((sub & 1) + 0.5f) * 0.5f;
        float yy = bx.sy + bx.bh * tys;
        float xx = bx.sx + bx.bw * txs;
        if (yy >= -1.f && yy <= bx.Wf && xx >= -1.f && xx <= bx.Wf) {
            float yc = fminf(fmaxf(yy, 0.f), bx.Wf - 1.f);
            float xc = fminf(fmaxf(xx, 0.f), bx.Wf - 1.f);
            float y0f = fminf(floorf(yc), bx.Wf - 2.f);
            float x0f = fminf(floorf(xc), bx.Wf - 2.f);
            float ly = yc - y0f, lx = xc - x0f;
            int y0 = (int)y0f, x0 = (int)x0f;
            const ushort_t* p00 = bx.memb + (size_t)(y0 * bx.W + x0) * HID;
            ushort4 u00 = *(const ushort4*)p00;
            ushort4 u01 = *(const ushort4*)(p00 + HID);
            ushort4 u10 = *(const ushort4*)(p00 + bx.W * HID);
            ushort4 u11 = *(const ushort4*)(p00 + bx.W * HID + HID);
            float w00 = (1.f - ly) * (1.f - lx), w01 = (1.f - ly) * lx;
            float w10 = ly * (1.f - lx), w11 = ly * lx;
            a0 += w00 * bfbits2f(u00.x) + w01 * bfbits2f(u01.x) + w10 * bfbits2f(u10.x) + w11 * bfbits2f(u11.x);
            a1 += w00 * bfbits2f(u00.y) + w01 * bfbits2f(u01.y) + w10 * bfbits2f(u10.y) + w11 * bfbits2f(u11.y);
            a2 += w00 * bfbits2f(u00.z) + w01 * bfbits2f(u01.z) + w10 * bfbits2f(u10.z) + w11 * bfbits2f(u11.z);
            a3 += w00 * bfbits2f(u00.w) + w01 * bfbits2f(u01.w) + w10 * bfbits2f(u10.w) + w11 * bfbits2f(u11.w);
        }
    }
    out.x = a0 * 0.25f; out.y = a1 * 0.25f; out.z = a2 * 0.25f; out.w = a3 * 0.25f;
}

// ---------------------------------------------------------------------------
// Merged prep: esplit(tgt) + 4x tsplit + memory->bf16  (one launch)
// ---------------------------------------------------------------------------
__device__ __forceinline__ void tsplit_body(const float* __restrict__ W,
                                            ushort_t* __restrict__ TH,
                                            ushort_t* __restrict__ TL,
                                            int K, int N, int kb, int nb,
                                            int perm, int tid, float (*sm)[65]) {
    for (int e = tid; e < 64 * 64; e += 256) {
        int kk = e >> 6, nn = e & 63;
        int kp = kb + kk;
        int ks = perm ? ((kp & 63) * 49 + (kp >> 6)) : kp;
        sm[kk][nn] = W[(size_t)ks * N + nb + nn];
    }
    __syncthreads();
    for (int e = tid; e < 64 * 64; e += 256) {
        int nn = e >> 6, kk = e & 63;
        ushort_t h, l;
        split_bf(sm[kk][nn], h, l);
        size_t o = (size_t)(nb + nn) * K + kb + kk;
        TH[o] = h; TL[o] = l;
    }
}

__global__ __launch_bounds__(256) void k_prep(
    const float* __restrict__ tgt, ushort_t* __restrict__ tgtH, ushort_t* __restrict__ tgtL,
    const float* __restrict__ a1w, ushort_t* __restrict__ a1wTH, ushort_t* __restrict__ a1wTL,
    const float* __restrict__ w1, ushort_t* __restrict__ w1TH, ushort_t* __restrict__ w1TL,
    const float* __restrict__ w2, ushort_t* __restrict__ w2TH, ushort_t* __restrict__ w2TL,
    const float* __restrict__ w3, ushort_t* __restrict__ w3TH, ushort_t* __restrict__ w3TL,
    const float* __restrict__ memory, ushort_t* __restrict__ mem16) {
    __shared__ float sm[64][65];
    const int tid = threadIdx.x;
    int b = blockIdx.x;
    if (b < 600) {                       // esplit on tgt (600*256 elems)
        int i = b * 256 + tid;
        ushort_t h, l;
        split_bf(tgt[i], h, l);
        tgtH[i] = h; tgtL[i] = l;
    } else if (b < 728) {                // a1w: K=256 x N=2048
        b -= 600;
        tsplit_body(a1w, a1wTH, a1wTL, 256, 2048, (b % 4) * 64, (b / 4) * 64, 0, tid, sm);
    } else if (b < 924) {                // w1: K=3136 x N=256, PERM
        b -= 728;
        tsplit_body(w1, w1TH, w1TL, 3136, 256, (b % 49) * 64, (b / 49) * 64, 1, tid, sm);
    } else if (b < 956) {                // w2: K=256 x N=512
        b -= 924;
        tsplit_body(w2, w2TH, w2TL, 256, 512, (b % 4) * 64, (b / 4) * 64, 0, tid, sm);
    } else if (b < 1020) {               // w3: K=512 x N=512
        b -= 956;
        tsplit_body(w3, w3TH, w3TL, 512, 512, (b % 8) * 64, (b / 8) * 64, 0, tid, sm);
    } else {                             // memory -> bf16: 2*21760*256 = 11141120 elems
        b -= 1020;                       // 10880 blocks, 1 float4/thread
        size_t i = (size_t)b * 256 + tid;   // float4 index
        float4 v = ((const float4*)memory)[i];
        ushort4 o;
        o.x = f2bfbits(v.x); o.y = f2bfbits(v.y);
        o.z = f2bfbits(v.z); o.w = f2bfbits(v.w);
        ((ushort4*)mem16)[i] = o;
    }
}

// ---------------------------------------------------------------------------
// bf16x3 MFMA GEMM (validated round 4). Tile 64x64, 4 waves.
// EPI: 0 = relu -> hi/lo bf16 ; 1 = relu -> fp32 ; 2 = sigmoid -> fp32
// ---------------------------------------------------------------------------
template <int EPI>
__global__ __launch_bounds__(256) void k_gmfma(
    const ushort_t* __restrict__ AH, const ushort_t* __restrict__ AL,
    const ushort_t* __restrict__ WH, const ushort_t* __restrict__ WL,
    const float* __restrict__ bias, float* __restrict__ Cf,
    ushort_t* __restrict__ CH, ushort_t* __restrict__ CL,
    int M, int N, int K) {
    __shared__ ushort_t As[2][64][40];
    __shared__ ushort_t Ws[2][64][40];

    const int tid = threadIdx.x;
    const int m0 = blockIdx.x * 64, n0 = blockIdx.y * 64;
    const int wv = tid >> 6, ln = tid & 63;
    const int row = tid >> 2, kc = tid & 3;
    const int gm = min(m0 + row, M - 1);
    const int gn = n0 + row;
    const int arow = wv * 16 + (ln & 15);
    const int koff = (ln >> 4) * 8;

    floatx4 acc[4];
#pragma unroll
    for (int t = 0; t < 4; ++t) acc[t] = (floatx4){0.f, 0.f, 0.f, 0.f};

    for (int k0 = 0; k0 < K; k0 += 32) {
        *(uint4*)&As[0][row][kc * 8] = *(const uint4*)(AH + (size_t)gm * K + k0 + kc * 8);
        *(uint4*)&As[1][row][kc * 8] = *(const uint4*)(AL + (size_t)gm * K + k0 + kc * 8);
        *(uint4*)&Ws[0][row][kc * 8] = *(const uint4*)(WH + (size_t)gn * K + k0 + kc * 8);
        *(uint4*)&Ws[1][row][kc * 8] = *(const uint4*)(WL + (size_t)gn * K + k0 + kc * 8);
        __syncthreads();

        short8 aH = *(short8*)&As[0][arow][koff];
        short8 aL = *(short8*)&As[1][arow][koff];
#pragma unroll
        for (int t = 0; t < 4; ++t) {
            short8 wH = *(short8*)&Ws[0][t * 16 + (ln & 15)][koff];
            short8 wL = *(short8*)&Ws[1][t * 16 + (ln & 15)][koff];
            acc[t] = __builtin_amdgcn_mfma_f32_16x16x32_bf16(aH, wH, acc[t], 0, 0, 0);
            acc[t] = __builtin_amdgcn_mfma_f32_16x16x32_bf16(aH, wL, acc[t], 0, 0, 0);
            acc[t] = __builtin_amdgcn_mfma_f32_16x16x32_bf16(aL, wH, acc[t], 0, 0, 0);
        }
        __syncthreads();
    }

#pragma unroll
    for (int t = 0; t < 4; ++t) {
        int n = n0 + t * 16 + (ln & 15);
        float bv = bias[n];
#pragma unroll
        for (int reg = 0; reg < 4; ++reg) {
            int m = m0 + wv * 16 + (ln >> 4) * 4 + reg;
            if (m < M) {
                float v = acc[t][reg] + bv;
                if (EPI == 0) {
                    v = fmaxf(v, 0.f);
                    ushort_t h, l;
                    split_bf(v, h, l);
                    CH[(size_t)m * N + n] = h;
                    CL[(size_t)m * N + n] = l;
                } else if (EPI == 1) {
                    Cf[(size_t)m * N + n] = fmaxf(v, 0.f);
                } else {
                    Cf[(size_t)m * N + n] = 1.f / (1.f + expf(-v));
                }
            }
        }
    }
}

// ---------------------------------------------------------------------------
// Per instance: ROI-align from bf16 memory -> roi bf16 (global + LDS);
// p1 VALU reading bf16 LDS (25 KB -> 6 blk/CU). Level-major swizzle.
// ---------------------------------------------------------------------------
__global__ __launch_bounds__(256) void k_roip1(
    const ushort_t* __restrict__ mem16, const float* __restrict__ refr,
    const float* __restrict__ p1w, const float* __restrict__ p1b,
    ushort_t* __restrict__ roi, ushort_t* __restrict__ pH,
    ushort_t* __restrict__ pL) {
    __shared__ __align__(16) ushort_t sm_roi[NCELL * HID];  // 25088 B -> 6 blk/CU

    const int tid  = threadIdx.x;
    const int wave = tid >> 6, lane = tid & 63;
    const int lvl = blockIdx.x / 600;      // level-major swizzle
    const int r   = blockIdx.x % 600;
    const int i2  = r * 4 + lvl;

    Box bx;
    load_box(refr, mem16, r, lvl, lane, bx);

    ushort_t* rbase = roi + (size_t)i2 * NCELL * HID;
    for (int cell = wave; cell < NCELL; cell += 4) {   // interleaved order
        float4 o;
        roi_cell(bx, cell, o);
        ushort4 pk;
        pk.x = f2bfbits(o.x); pk.y = f2bfbits(o.y);
        pk.z = f2bfbits(o.z); pk.w = f2bfbits(o.w);
        *(ushort4*)&sm_roi[cell * HID + lane * 4] = pk;
        *(ushort4*)&rbase[cell * HID + lane * 4] = pk;
    }
    __syncthreads();

    // p1: 256->64 per cell; bf16 LDS reads, even/odd partial sums (r8 order)
    {
        const int d = tid & 63;
        const int grp = tid >> 6;
        const int cell0 = grp * 13;
        int off[13];
#pragma unroll
        for (int i = 0; i < 13; ++i) off[i] = min(cell0 + i, NCELL - 1) * HID;
        float acc0[13], acc1[13];
#pragma unroll
        for (int i = 0; i < 13; ++i) { acc0[i] = 0.f; acc1[i] = 0.f; }
        for (int c = 0; c < HID; c += 4) {
            float w0 = p1w[(size_t)c * 64 + d];
            float w1 = p1w[(size_t)(c + 1) * 64 + d];
            float w2 = p1w[(size_t)(c + 2) * 64 + d];
            float w3 = p1w[(size_t)(c + 3) * 64 + d];
#pragma unroll
            for (int i = 0; i < 13; ++i) {
                ushort4 rv = *(ushort4*)&sm_roi[off[i] + c];
                acc0[i] += bfbits2f(rv.x) * w0;
                acc1[i] += bfbits2f(rv.y) * w1;
                acc0[i] += bfbits2f(rv.z) * w2;
                acc1[i] += bfbits2f(rv.w) * w3;
            }
        }
        float bias = p1b[d];
        size_t pbase = (size_t)i2 * 3136;
#pragma unroll
        for (int i = 0; i < 13; ++i) {
            int cell = cell0 + i;
            if (cell < NCELL) {
                float v = fmaxf(acc0[i] + acc1[i] + bias, 0.f);
                ushort_t h, l;
                split_bf(v, h, l);
                pH[pbase + cell * 64 + d] = h;
                pL[pbase + cell * 64 + d] = l;
            }
        }
    }
}

// ---------------------------------------------------------------------------
// Layer 4: pts = tanh(h3 @ w4 + b4)
// ---------------------------------------------------------------------------
__global__ __launch_bounds__(256) void k_l4(const float* __restrict__ h3,
                                            const float* __restrict__ w4,
                                            const float* __restrict__ b4,
                                            float* __restrict__ pts) {
    __shared__ __align__(16) float sm[16 * 512];
    const int tid = threadIdx.x;
    const int r0 = blockIdx.x * 16;
    const float4* src = (const float4*)(h3 + (size_t)r0 * 512);
    float4* dst = (float4*)sm;
    for (int i = tid; i < 16 * 128; i += 256) dst[i] = src[i];
    __syncthreads();
    const int row = tid >> 4, col = tid & 15;
    float acc = 0.f;
    for (int k = 0; k < 512; ++k) acc += sm[row * 512 + k] * w4[k * 16 + col];
    pts[(size_t)(r0 + row) * 16 + col] = tanhf(acc + b4[col]);
}

// ---------------------------------------------------------------------------
// Fused: per query r: grid_sample(roi,pts)*gate -> qe (LDS) -> logits ->
// softmax -> weighted sum -> out.  (validated round 6)
// ---------------------------------------------------------------------------
__global__ __launch_bounds__(256) void k_fuse(
    const ushort_t* __restrict__ roi, const float* __restrict__ pts,
    const float* __restrict__ gate, const float* __restrict__ w,
    const float* __restrict__ bias, float* __restrict__ out) {
    __shared__ float sm_qe[32 * HID];   // 32 KB
    __shared__ float sm_hd[32][4];
    __shared__ float sm_l[32];
    __shared__ float sm_e[32];

    const int tid = threadIdx.x;
    const int r = blockIdx.x;

    if (tid < 32) {
        int lvl = tid >> 3, h = tid & 7;
        size_t i2 = (size_t)r * 4 + lvl;
        float gx = pts[i2 * 16 + h * 2];
        float gy = pts[i2 * 16 + h * 2 + 1];
        float ix = ((gx + 1.f) * 7.f - 1.f) * 0.5f;
        float iy = ((gy + 1.f) * 7.f - 1.f) * 0.5f;
        float x0f = floorf(ix), y0f = floorf(iy);
        sm_hd[tid][0] = x0f;
        sm_hd[tid][1] = y0f;
        sm_hd[tid][2] = ix - x0f;
        sm_hd[tid][3] = iy - y0f;
    }
    __syncthreads();

    const float* grow = gate + (size_t)r * 2048;
#pragma unroll
    for (int j = 0; j < 32; ++j) {
        int lvl = j >> 3, h = j & 7;
        const ushort_t* rbase = roi + ((size_t)r * 4 + lvl) * NCELL * HID;
        float x0f = sm_hd[j][0], y0f = sm_hd[j][1];
        float lx = sm_hd[j][2], ly = sm_hd[j][3];
        int x0 = (int)x0f, y0 = (int)y0f;
        float v = 0.f;
#pragma unroll
        for (int dy = 0; dy < 2; ++dy) {
            int yi = y0 + dy;
            if (yi < 0 || yi >= 7) continue;
            float wy = dy ? ly : 1.f - ly;
#pragma unroll
            for (int dx = 0; dx < 2; ++dx) {
                int xi = x0 + dx;
                if (xi < 0 || xi >= 7) continue;
                float wx = dx ? lx : 1.f - lx;
                v += wy * wx * bfbits2f(rbase[(yi * 7 + xi) * HID + tid]);
            }
        }
        sm_qe[j * HID + tid] = v * grow[h * HID + tid];
    }
    __syncthreads();

    const int j = tid >> 3, sub = tid & 7;
    float part = 0.f;
    const int cbase = sub * 32;
    for (int c = 0; c < 32; ++c) part += sm_qe[j * HID + cbase + c] * w[cbase + c];
    part += __shfl_down(part, 4);
    part += __shfl_down(part, 2);
    part += __shfl_down(part, 1);
    if (sub == 0) sm_l[j] = part + bias[0];
    __syncthreads();
    if (tid < 32) {
        float m = -1e30f;
        for (int i = 0; i < 32; ++i) m = fmaxf(m, sm_l[i]);
        sm_e[tid] = expf(sm_l[tid] - m);
    }
    __syncthreads();
    float denom = 0.f;
    for (int i = 0; i < 32; ++i) denom += sm_e[i];
    float inv = 1.f / denom;
    float acc = 0.f;
    for (int jj = 0; jj < 32; ++jj) acc += sm_qe[jj * HID + tid] * sm_e[jj];
    out[(size_t)r * HID + tid] = acc * inv;
}

// ---------------------------------------------------------------------------
extern "C" void kernel_launch(void* const* d_in, const int* in_sizes, int n_in,
                              void* d_out, int out_size, void* d_ws, size_t ws_size,
                              hipStream_t stream) {
    const float* tgt    = (const float*)d_in[0];
    const float* memory = (const float*)d_in[1];
    const float* refr   = (const float*)d_in[2];
    const float* p1w = (const float*)d_in[4];
    const float* p1b = (const float*)d_in[5];
    const float* w1  = (const float*)d_in[6];
    const float* b1  = (const float*)d_in[7];
    const float* w2  = (const float*)d_in[8];
    const float* b2  = (const float*)d_in[9];
    const float* w3  = (const float*)d_in[10];
    const float* b3  = (const float*)d_in[11];
    const float* w4  = (const float*)d_in[12];
    const float* b4  = (const float*)d_in[13];
    const float* a1w = (const float*)d_in[14];
    const float* a1b = (const float*)d_in[15];
    const float* a2w = (const float*)d_in[16];
    const float* a2b = (const float*)d_in[17];
    float* out = (float*)d_out;

    size_t off = 0;
    auto alloc = [&](size_t bytes) {
        void* p = (char*)d_ws + off;
        off += (bytes + 255) & ~(size_t)255;
        return p;
    };
    float*    gate  = (float*)alloc((size_t)600 * 2048 * 4);
    ushort_t* mem16 = (ushort_t*)alloc((size_t)2 * TOTAL * HID * 2);
    ushort_t* roi   = (ushort_t*)alloc((size_t)2400 * NCELL * HID * 2);
    ushort_t* pHb   = (ushort_t*)alloc((size_t)2400 * 3136 * 2);
    ushort_t* pLb   = (ushort_t*)alloc((size_t)2400 * 3136 * 2);
    ushort_t* h1H   = (ushort_t*)alloc((size_t)2400 * 256 * 2);
    ushort_t* h1L   = (ushort_t*)alloc((size_t)2400 * 256 * 2);
    ushort_t* h2H   = (ushort_t*)alloc((size_t)2400 * 512 * 2);
    ushort_t* h2L   = (ushort_t*)alloc((size_t)2400 * 512 * 2);
    float*    h3    = (float*)alloc((size_t)2400 * 512 * 4);
    float*    pts   = (float*)alloc((size_t)2400 * 16 * 4);
    ushort_t* tgtH  = (ushort_t*)alloc((size_t)600 * 256 * 2);
    ushort_t* tgtL  = (ushort_t*)alloc((size_t)600 * 256 * 2);
    ushort_t* a1wTH = (ushort_t*)alloc((size_t)2048 * 256 * 2);
    ushort_t* a1wTL = (ushort_t*)alloc((size_t)2048 * 256 * 2);
    ushort_t* w1TH  = (ushort_t*)alloc((size_t)256 * 3136 * 2);
    ushort_t* w1TL  = (ushort_t*)alloc((size_t)256 * 3136 * 2);
    ushort_t* w2TH  = (ushort_t*)alloc((size_t)512 * 256 * 2);
    ushort_t* w2TL  = (ushort_t*)alloc((size_t)512 * 256 * 2);
    ushort_t* w3TH  = (ushort_t*)alloc((size_t)512 * 512 * 2);
    ushort_t* w3TL  = (ushort_t*)alloc((size_t)512 * 512 * 2);

    // merged prep (esplit + 4 tsplits + memory->bf16): 1020 + 10880 blocks
    hipLaunchKernelGGL(k_prep, dim3(11900), dim3(256), 0, stream,
                       tgt, tgtH, tgtL, a1w, a1wTH, a1wTL,
                       w1, w1TH, w1TL, w2, w2TH, w2TL, w3, w3TH, w3TL,
                       memory, mem16);

    // gate = sigmoid(tgt @ a1w + a1b)
    hipLaunchKernelGGL((k_gmfma<2>), dim3(10, 32), dim3(256), 0, stream,
                       tgtH, tgtL, a1wTH, a1wTL, a1b, gate, (ushort_t*)0, (ushort_t*)0,
                       600, 2048, 256);
    // roi + p1 (level-major swizzle, bf16 memory, bf16 LDS)
    hipLaunchKernelGGL(k_roip1, dim3(2400), dim3(256), 0, stream,
                       mem16, refr, p1w, p1b, roi, pHb, pLb);
    // MLP
    hipLaunchKernelGGL((k_gmfma<0>), dim3(38, 4), dim3(256), 0, stream,
                       pHb, pLb, w1TH, w1TL, b1, (float*)0, h1H, h1L, 2400, 256, 3136);
    hipLaunchKernelGGL((k_gmfma<0>), dim3(38, 8), dim3(256), 0, stream,
                       h1H, h1L, w2TH, w2TL, b2, (float*)0, h2H, h2L, 2400, 512, 256);
    hipLaunchKernelGGL((k_gmfma<1>), dim3(38, 8), dim3(256), 0, stream,
                       h2H, h2L, w3TH, w3TL, b3, h3, (ushort_t*)0, (ushort_t*)0,
                       2400, 512, 512);
    hipLaunchKernelGGL(k_l4, dim3(150), dim3(256), 0, stream, h3, w4, b4, pts);
    // fused sample + softmax-output
    hipLaunchKernelGGL(k_fuse, dim3(600), dim3(256), 0, stream,
                       roi, pts, gate, a2w, a2b, out);
}

// Round 10
// 424.959 us; speedup vs baseline: 1.2146x; 1.2146x over previous
//
#include <hip/hip_runtime.h>
#include <hip/hip_bf16.h>

#define NQ     300
#define NH     8
#define HID    256
#define NLVL   4
#define NCELL  49
#define TOTAL  21760

typedef unsigned short ushort_t;
typedef __attribute__((ext_vector_type(8))) short short8;
typedef __attribute__((ext_vector_type(4))) float floatx4;

__device__ __forceinline__ float bfbits2f(ushort_t u) {
    union { unsigned int i; float f; } x;
    x.i = ((unsigned int)u) << 16;
    return x.f;
}
__device__ __forceinline__ ushort_t f2bfbits(float v) {
    __hip_bfloat16 h = __float2bfloat16(v);
    return *(ushort_t*)&h;
}
__device__ __forceinline__ void split_bf(float v, ushort_t& hi, ushort_t& lo) {
    __hip_bfloat16 h = __float2bfloat16(v);
    hi = *(ushort_t*)&h;
    float hv = __bfloat162float(h);
    __hip_bfloat16 l = __float2bfloat16(v - hv);
    lo = *(ushort_t*)&l;
}

// ---------------------------------------------------------------------------
// ROI helpers — bf16 memory (validated round 9)
// ---------------------------------------------------------------------------
struct Box {
    float sx, sy, bw, bh, Wf;
    int W;
    const ushort_t* memb;
};

__device__ __forceinline__ void load_box(const float* __restrict__ refr,
                                         const ushort_t* __restrict__ mem16,
                                         int r, int lvl, int lane, Box& bx) {
    const int lvl_hw[4] = {128, 64, 32, 16};
    const int lvl_s[4]  = {0, 16384, 20480, 21504};
    const int b = r / NQ;
    bx.W  = lvl_hw[lvl];
    bx.Wf = (float)bx.W;
    const float* rp = refr + ((size_t)r * NLVL + lvl) * 6;
    float cx = rp[0], cy = rp[1];
    float dl = rp[2], dt = rp[3], dr = rp[4], db = rp[5];
    float x1 = fminf(fmaxf(cx - dl, 0.f), 1.f) * bx.Wf;
    float y1 = fminf(fmaxf(cy - dt, 0.f), 1.f) * bx.Wf;
    float x2 = fminf(fmaxf(cx + dr, 0.f), 1.f) * bx.Wf;
    float y2 = fminf(fmaxf(cy + db, 0.f), 1.f) * bx.Wf;
    bx.sx = x1 - 0.5f;
    bx.sy = y1 - 0.5f;
    bx.bw = (x2 - x1) * (1.f / 7.f);
    bx.bh = (y2 - y1) * (1.f / 7.f);
    bx.memb = mem16 + ((size_t)b * TOTAL + lvl_s[lvl]) * HID + lane * 4;
}

__device__ __forceinline__ void roi_cell(const Box& bx, int cell, float4& out) {
    const int ph = cell / 7, pw = cell % 7;
    float a0 = 0.f, a1 = 0.f, a2 = 0.f, a3 = 0.f;
#pragma unroll
    for (int sub = 0; sub < 4; ++sub) {
        const float tys = (float)ph + ((sub >> 1) + 0.5f) * 0.5f;
        const float txs = (float)pw + ((sub & 1) + 0.5f) * 0.5f;
        float yy = bx.sy + bx.bh * tys;
        float xx = bx.sx + bx.bw * txs;
        if (yy >= -1.f && yy <= bx.Wf && xx >= -1.f && xx <= bx.Wf) {
            float yc = fminf(fmaxf(yy, 0.f), bx.Wf - 1.f);
            float xc = fminf(fmaxf(xx, 0.f), bx.Wf - 1.f);
            float y0f = fminf(floorf(yc), bx.Wf - 2.f);
            float x0f = fminf(floorf(xc), bx.Wf - 2.f);
            float ly = yc - y0f, lx = xc - x0f;
            int y0 = (int)y0f, x0 = (int)x0f;
            const ushort_t* p00 = bx.memb + (size_t)(y0 * bx.W + x0) * HID;
            ushort4 u00 = *(const ushort4*)p00;
            ushort4 u01 = *(const ushort4*)(p00 + HID);
            ushort4 u10 = *(const ushort4*)(p00 + bx.W * HID);
            ushort4 u11 = *(const ushort4*)(p00 + bx.W * HID + HID);
            float w00 = (1.f - ly) * (1.f - lx), w01 = (1.f - ly) * lx;
            float w10 = ly * (1.f - lx), w11 = ly * lx;
            a0 += w00 * bfbits2f(u00.x) + w01 * bfbits2f(u01.x) + w10 * bfbits2f(u10.x) + w11 * bfbits2f(u11.x);
            a1 += w00 * bfbits2f(u00.y) + w01 * bfbits2f(u01.y) + w10 * bfbits2f(u10.y) + w11 * bfbits2f(u11.y);
            a2 += w00 * bfbits2f(u00.z) + w01 * bfbits2f(u01.z) + w10 * bfbits2f(u10.z) + w11 * bfbits2f(u11.z);
            a3 += w00 * bfbits2f(u00.w) + w01 * bfbits2f(u01.w) + w10 * bfbits2f(u10.w) + w11 * bfbits2f(u11.w);
        }
    }
    out.x = a0 * 0.25f; out.y = a1 * 0.25f; out.z = a2 * 0.25f; out.w = a3 * 0.25f;
}

// ---------------------------------------------------------------------------
// Merged prep: esplit(tgt) + 5x tsplit + memory->bf16  (one launch)
// ---------------------------------------------------------------------------
__device__ __forceinline__ void tsplit_body(const float* __restrict__ W,
                                            ushort_t* __restrict__ TH,
                                            ushort_t* __restrict__ TL,
                                            int K, int N, int kb, int nb,
                                            int perm, int tid, float (*sm)[65]) {
    for (int e = tid; e < 64 * 64; e += 256) {
        int kk = e >> 6, nn = e & 63;
        int kp = kb + kk;
        int ks = perm ? ((kp & 63) * 49 + (kp >> 6)) : kp;
        sm[kk][nn] = W[(size_t)ks * N + nb + nn];
    }
    __syncthreads();
    for (int e = tid; e < 64 * 64; e += 256) {
        int nn = e >> 6, kk = e & 63;
        ushort_t h, l;
        split_bf(sm[kk][nn], h, l);
        size_t o = (size_t)(nb + nn) * K + kb + kk;
        TH[o] = h; TL[o] = l;
    }
}

__global__ __launch_bounds__(256) void k_prep(
    const float* __restrict__ tgt, ushort_t* __restrict__ tgtH, ushort_t* __restrict__ tgtL,
    const float* __restrict__ a1w, ushort_t* __restrict__ a1wTH, ushort_t* __restrict__ a1wTL,
    const float* __restrict__ w1, ushort_t* __restrict__ w1TH, ushort_t* __restrict__ w1TL,
    const float* __restrict__ w2, ushort_t* __restrict__ w2TH, ushort_t* __restrict__ w2TL,
    const float* __restrict__ w3, ushort_t* __restrict__ w3TH, ushort_t* __restrict__ w3TL,
    const float* __restrict__ p1w, ushort_t* __restrict__ p1wTH, ushort_t* __restrict__ p1wTL,
    const float* __restrict__ memory, ushort_t* __restrict__ mem16) {
    __shared__ float sm[64][65];
    const int tid = threadIdx.x;
    int b = blockIdx.x;
    if (b < 600) {                       // esplit on tgt (600*256 elems)
        int i = b * 256 + tid;
        ushort_t h, l;
        split_bf(tgt[i], h, l);
        tgtH[i] = h; tgtL[i] = l;
    } else if (b < 728) {                // a1w: K=256 x N=2048
        b -= 600;
        tsplit_body(a1w, a1wTH, a1wTL, 256, 2048, (b % 4) * 64, (b / 4) * 64, 0, tid, sm);
    } else if (b < 924) {                // w1: K=3136 x N=256, PERM
        b -= 728;
        tsplit_body(w1, w1TH, w1TL, 3136, 256, (b % 49) * 64, (b / 49) * 64, 1, tid, sm);
    } else if (b < 956) {                // w2: K=256 x N=512
        b -= 924;
        tsplit_body(w2, w2TH, w2TL, 256, 512, (b % 4) * 64, (b / 4) * 64, 0, tid, sm);
    } else if (b < 1020) {               // w3: K=512 x N=512
        b -= 956;
        tsplit_body(w3, w3TH, w3TL, 512, 512, (b % 8) * 64, (b / 8) * 64, 0, tid, sm);
    } else if (b < 1024) {               // p1w: K=256 x N=64
        b -= 1020;
        tsplit_body(p1w, p1wTH, p1wTL, 256, 64, b * 64, 0, 0, tid, sm);
    } else {                             // memory -> bf16 (10880 blocks)
        b -= 1024;
        size_t i = (size_t)b * 256 + tid;   // float4 index
        float4 v = ((const float4*)memory)[i];
        ushort4 o;
        o.x = f2bfbits(v.x); o.y = f2bfbits(v.y);
        o.z = f2bfbits(v.z); o.w = f2bfbits(v.w);
        ((ushort4*)mem16)[i] = o;
    }
}

// ---------------------------------------------------------------------------
// bf16x3 MFMA GEMM (validated round 4). Tile 64x64, 4 waves.
// EPI: 0 = relu -> hi/lo bf16 ; 1 = relu -> fp32 ; 2 = sigmoid -> fp32
// AX : 1 = A is exactly bf16 (AL unused; skip lo-term MFMA)
// ---------------------------------------------------------------------------
template <int EPI, int AX>
__global__ __launch_bounds__(256) void k_gmfma(
    const ushort_t* __restrict__ AH, const ushort_t* __restrict__ AL,
    const ushort_t* __restrict__ WH, const ushort_t* __restrict__ WL,
    const float* __restrict__ bias, float* __restrict__ Cf,
    ushort_t* __restrict__ CH, ushort_t* __restrict__ CL,
    int M, int N, int K) {
    __shared__ ushort_t As[AX ? 1 : 2][64][40];
    __shared__ ushort_t Ws[2][64][40];

    const int tid = threadIdx.x;
    const int m0 = blockIdx.x * 64, n0 = blockIdx.y * 64;
    const int wv = tid >> 6, ln = tid & 63;
    const int row = tid >> 2, kc = tid & 3;
    const int gm = min(m0 + row, M - 1);
    const int gn = n0 + row;
    const int arow = wv * 16 + (ln & 15);
    const int koff = (ln >> 4) * 8;

    floatx4 acc[4];
#pragma unroll
    for (int t = 0; t < 4; ++t) acc[t] = (floatx4){0.f, 0.f, 0.f, 0.f};

    for (int k0 = 0; k0 < K; k0 += 32) {
        *(uint4*)&As[0][row][kc * 8] = *(const uint4*)(AH + (size_t)gm * K + k0 + kc * 8);
        if constexpr (!AX)
            *(uint4*)&As[AX ? 0 : 1][row][kc * 8] = *(const uint4*)(AL + (size_t)gm * K + k0 + kc * 8);
        *(uint4*)&Ws[0][row][kc * 8] = *(const uint4*)(WH + (size_t)gn * K + k0 + kc * 8);
        *(uint4*)&Ws[1][row][kc * 8] = *(const uint4*)(WL + (size_t)gn * K + k0 + kc * 8);
        __syncthreads();

        short8 aH = *(short8*)&As[0][arow][koff];
        short8 aL = aH;
        if constexpr (!AX) aL = *(short8*)&As[AX ? 0 : 1][arow][koff];
#pragma unroll
        for (int t = 0; t < 4; ++t) {
            short8 wH = *(short8*)&Ws[0][t * 16 + (ln & 15)][koff];
            short8 wL = *(short8*)&Ws[1][t * 16 + (ln & 15)][koff];
            acc[t] = __builtin_amdgcn_mfma_f32_16x16x32_bf16(aH, wH, acc[t], 0, 0, 0);
            acc[t] = __builtin_amdgcn_mfma_f32_16x16x32_bf16(aH, wL, acc[t], 0, 0, 0);
            if constexpr (!AX)
                acc[t] = __builtin_amdgcn_mfma_f32_16x16x32_bf16(aL, wH, acc[t], 0, 0, 0);
        }
        __syncthreads();
    }

#pragma unroll
    for (int t = 0; t < 4; ++t) {
        int n = n0 + t * 16 + (ln & 15);
        float bv = bias[n];
#pragma unroll
        for (int reg = 0; reg < 4; ++reg) {
            int m = m0 + wv * 16 + (ln >> 4) * 4 + reg;
            if (m < M) {
                float v = acc[t][reg] + bv;
                if (EPI == 0) {
                    v = fmaxf(v, 0.f);
                    ushort_t h, l;
                    split_bf(v, h, l);
                    CH[(size_t)m * N + n] = h;
                    CL[(size_t)m * N + n] = l;
                } else if (EPI == 1) {
                    Cf[(size_t)m * N + n] = fmaxf(v, 0.f);
                } else {
                    Cf[(size_t)m * N + n] = 1.f / (1.f + expf(-v));
                }
            }
        }
    }
}

// ---------------------------------------------------------------------------
// Per instance: ROI-align only -> roi bf16 global. No LDS, no barrier.
// Level-major swizzle (validated r7). p1 is done by the batched GEMM.
// ---------------------------------------------------------------------------
__global__ __launch_bounds__(256) void k_roi(
    const ushort_t* __restrict__ mem16, const float* __restrict__ refr,
    ushort_t* __restrict__ roi) {
    const int tid  = threadIdx.x;
    const int wave = tid >> 6, lane = tid & 63;
    const int lvl = blockIdx.x / 600;
    const int r   = blockIdx.x % 600;
    const int i2  = r * 4 + lvl;

    Box bx;
    load_box(refr, mem16, r, lvl, lane, bx);

    ushort_t* rbase = roi + (size_t)i2 * NCELL * HID;
    for (int cell = wave; cell < NCELL; cell += 4) {
        float4 o;
        roi_cell(bx, cell, o);
        ushort4 pk;
        pk.x = f2bfbits(o.x); pk.y = f2bfbits(o.y);
        pk.z = f2bfbits(o.z); pk.w = f2bfbits(o.w);
        *(ushort4*)&rbase[cell * HID + lane * 4] = pk;
    }
}

// ---------------------------------------------------------------------------
// Fused: per query r: pts = tanh(h3@w4+b4) (4 rows) -> grid_sample*gate ->
// qe (LDS) -> logits -> softmax -> weighted sum -> out.
// ---------------------------------------------------------------------------
__global__ __launch_bounds__(256) void k_fuse(
    const ushort_t* __restrict__ roi, const float* __restrict__ h3,
    const float* __restrict__ w4, const float* __restrict__ b4,
    const float* __restrict__ gate, const float* __restrict__ w,
    const float* __restrict__ bias, float* __restrict__ out) {
    __shared__ float sm_qe[32 * HID];   // 32 KB; first 2048 floats alias h3 stage
    __shared__ float sm_pts[64];
    __shared__ float sm_hd[32][4];
    __shared__ float sm_l[32];
    __shared__ float sm_e[32];

    const int tid = threadIdx.x;
    const int r = blockIdx.x;

    // ---- stage h3 rows 4r..4r+3 into LDS (aliases sm_qe) ----
    float* sm_h3 = sm_qe;
    {
        const float4* src = (const float4*)(h3 + (size_t)r * 4 * 512);
        float4* dst = (float4*)sm_h3;
        for (int i = tid; i < 512; i += 256) dst[i] = src[i];
    }
    __syncthreads();

    // ---- pts = tanh(h3 @ w4 + b4): 64 outputs, 4 threads each ----
    {
        const int o = tid >> 2, s = tid & 3;     // o: row*16+col
        const int row = o >> 4, col = o & 15;
        float part = 0.f;
        const int kb = s * 128;
        for (int k = kb; k < kb + 128; ++k)
            part += sm_h3[row * 512 + k] * w4[k * 16 + col];
        part += __shfl_down(part, 2);
        part += __shfl_down(part, 1);
        if (s == 0) sm_pts[row * 16 + col] = tanhf(part + b4[col]);
    }
    __syncthreads();

    if (tid < 32) {
        int lvl = tid >> 3, h = tid & 7;
        float gx = sm_pts[lvl * 16 + h * 2];
        float gy = sm_pts[lvl * 16 + h * 2 + 1];
        float ix = ((gx + 1.f) * 7.f - 1.f) * 0.5f;
        float iy = ((gy + 1.f) * 7.f - 1.f) * 0.5f;
        float x0f = floorf(ix), y0f = floorf(iy);
        sm_hd[tid][0] = x0f;
        sm_hd[tid][1] = y0f;
        sm_hd[tid][2] = ix - x0f;
        sm_hd[tid][3] = iy - y0f;
    }
    __syncthreads();

    const float* grow = gate + (size_t)r * 2048;
#pragma unroll
    for (int j = 0; j < 32; ++j) {
        int lvl = j >> 3, h = j & 7;
        const ushort_t* rbase = roi + ((size_t)r * 4 + lvl) * NCELL * HID;
        float x0f = sm_hd[j][0], y0f = sm_hd[j][1];
        float lx = sm_hd[j][2], ly = sm_hd[j][3];
        int x0 = (int)x0f, y0 = (int)y0f;
        float v = 0.f;
#pragma unroll
        for (int dy = 0; dy < 2; ++dy) {
            int yi = y0 + dy;
            if (yi < 0 || yi >= 7) continue;
            float wy = dy ? ly : 1.f - ly;
#pragma unroll
            for (int dx = 0; dx < 2; ++dx) {
                int xi = x0 + dx;
                if (xi < 0 || xi >= 7) continue;
                float wx = dx ? lx : 1.f - lx;
                v += wy * wx * bfbits2f(rbase[(yi * 7 + xi) * HID + tid]);
            }
        }
        sm_qe[j * HID + tid] = v * grow[h * HID + tid];
    }
    __syncthreads();

    const int j = tid >> 3, sub = tid & 7;
    float part = 0.f;
    const int cbase = sub * 32;
    for (int c = 0; c < 32; ++c) part += sm_qe[j * HID + cbase + c] * w[cbase + c];
    part += __shfl_down(part, 4);
    part += __shfl_down(part, 2);
    part += __shfl_down(part, 1);
    if (sub == 0) sm_l[j] = part + bias[0];
    __syncthreads();
    if (tid < 32) {
        float m = -1e30f;
        for (int i = 0; i < 32; ++i) m = fmaxf(m, sm_l[i]);
        sm_e[tid] = expf(sm_l[tid] - m);
    }
    __syncthreads();
    float denom = 0.f;
    for (int i = 0; i < 32; ++i) denom += sm_e[i];
    float inv = 1.f / denom;
    float acc = 0.f;
    for (int jj = 0; jj < 32; ++jj) acc += sm_qe[jj * HID + tid] * sm_e[jj];
    out[(size_t)r * HID + tid] = acc * inv;
}

// ---------------------------------------------------------------------------
extern "C" void kernel_launch(void* const* d_in, const int* in_sizes, int n_in,
                              void* d_out, int out_size, void* d_ws, size_t ws_size,
                              hipStream_t stream) {
    const float* tgt    = (const float*)d_in[0];
    const float* memory = (const float*)d_in[1];
    const float* refr   = (const float*)d_in[2];
    const float* p1w = (const float*)d_in[4];
    const float* p1b = (const float*)d_in[5];
    const float* w1  = (const float*)d_in[6];
    const float* b1  = (const float*)d_in[7];
    const float* w2  = (const float*)d_in[8];
    const float* b2  = (const float*)d_in[9];
    const float* w3  = (const float*)d_in[10];
    const float* b3  = (const float*)d_in[11];
    const float* w4  = (const float*)d_in[12];
    const float* b4  = (const float*)d_in[13];
    const float* a1w = (const float*)d_in[14];
    const float* a1b = (const float*)d_in[15];
    const float* a2w = (const float*)d_in[16];
    const float* a2b = (const float*)d_in[17];
    float* out = (float*)d_out;

    size_t off = 0;
    auto alloc = [&](size_t bytes) {
        void* p = (char*)d_ws + off;
        off += (bytes + 255) & ~(size_t)255;
        return p;
    };
    float*    gate  = (float*)alloc((size_t)600 * 2048 * 4);
    ushort_t* mem16 = (ushort_t*)alloc((size_t)2 * TOTAL * HID * 2);
    ushort_t* roi   = (ushort_t*)alloc((size_t)2400 * NCELL * HID * 2);
    ushort_t* pHb   = (ushort_t*)alloc((size_t)2400 * 3136 * 2);
    ushort_t* pLb   = (ushort_t*)alloc((size_t)2400 * 3136 * 2);
    ushort_t* h1H   = (ushort_t*)alloc((size_t)2400 * 256 * 2);
    ushort_t* h1L   = (ushort_t*)alloc((size_t)2400 * 256 * 2);
    ushort_t* h2H   = (ushort_t*)alloc((size_t)2400 * 512 * 2);
    ushort_t* h2L   = (ushort_t*)alloc((size_t)2400 * 512 * 2);
    float*    h3    = (float*)alloc((size_t)2400 * 512 * 4);
    ushort_t* tgtH  = (ushort_t*)alloc((size_t)600 * 256 * 2);
    ushort_t* tgtL  = (ushort_t*)alloc((size_t)600 * 256 * 2);
    ushort_t* a1wTH = (ushort_t*)alloc((size_t)2048 * 256 * 2);
    ushort_t* a1wTL = (ushort_t*)alloc((size_t)2048 * 256 * 2);
    ushort_t* w1TH  = (ushort_t*)alloc((size_t)256 * 3136 * 2);
    ushort_t* w1TL  = (ushort_t*)alloc((size_t)256 * 3136 * 2);
    ushort_t* w2TH  = (ushort_t*)alloc((size_t)512 * 256 * 2);
    ushort_t* w2TL  = (ushort_t*)alloc((size_t)512 * 256 * 2);
    ushort_t* w3TH  = (ushort_t*)alloc((size_t)512 * 512 * 2);
    ushort_t* w3TL  = (ushort_t*)alloc((size_t)512 * 512 * 2);
    ushort_t* p1wTH = (ushort_t*)alloc((size_t)64 * 256 * 2);
    ushort_t* p1wTL = (ushort_t*)alloc((size_t)64 * 256 * 2);

    // merged prep: 1024 range blocks + 10880 memory-conversion blocks
    hipLaunchKernelGGL(k_prep, dim3(11904), dim3(256), 0, stream,
                       tgt, tgtH, tgtL, a1w, a1wTH, a1wTL,
                       w1, w1TH, w1TL, w2, w2TH, w2TL, w3, w3TH, w3TL,
                       p1w, p1wTH, p1wTL, memory, mem16);

    // gate = sigmoid(tgt @ a1w + a1b)
    hipLaunchKernelGGL((k_gmfma<2, 0>), dim3(10, 32), dim3(256), 0, stream,
                       tgtH, tgtL, a1wTH, a1wTL, a1b, gate, (ushort_t*)0, (ushort_t*)0,
                       600, 2048, 256);
    // roi (level-major swizzle, bf16 memory, no LDS)
    hipLaunchKernelGGL(k_roi, dim3(2400), dim3(256), 0, stream, mem16, refr, roi);
    // p1 as one batched GEMM: (2400*49 x 256) @ (256 x 64), A exact-bf16
    hipLaunchKernelGGL((k_gmfma<0, 1>), dim3(1838, 1), dim3(256), 0, stream,
                       roi, (ushort_t*)0, p1wTH, p1wTL, p1b, (float*)0, pHb, pLb,
                       2400 * NCELL, 64, 256);
    // MLP
    hipLaunchKernelGGL((k_gmfma<0, 0>), dim3(38, 4), dim3(256), 0, stream,
                       pHb, pLb, w1TH, w1TL, b1, (float*)0, h1H, h1L, 2400, 256, 3136);
    hipLaunchKernelGGL((k_gmfma<0, 0>), dim3(38, 8), dim3(256), 0, stream,
                       h1H, h1L, w2TH, w2TL, b2, (float*)0, h2H, h2L, 2400, 512, 256);
    hipLaunchKernelGGL((k_gmfma<1, 0>), dim3(38, 8), dim3(256), 0, stream,
                       h2H, h2L, w3TH, w3TL, b3, h3, (ushort_t*)0, (ushort_t*)0,
                       2400, 512, 512);
    // fused l4 + sample + softmax-output
    hipLaunchKernelGGL(k_fuse, dim3(600), dim3(256), 0, stream,
                       roi, h3, w4, b4, gate, a2w, a2b, out);
}

// Round 11
// 354.403 us; speedup vs baseline: 1.4564x; 1.1991x over previous
//
#include <hip/hip_runtime.h>
#include <hip/hip_bf16.h>

#define NQ     300
#define NH     8
#define HID    256
#define NLVL   4
#define NCELL  49
#define TOTAL  21760

typedef unsigned short ushort_t;
typedef __attribute__((ext_vector_type(8))) short short8;
typedef __attribute__((ext_vector_type(4))) float floatx4;

__device__ __forceinline__ float bfbits2f(ushort_t u) {
    union { unsigned int i; float f; } x;
    x.i = ((unsigned int)u) << 16;
    return x.f;
}
__device__ __forceinline__ ushort_t f2bfbits(float v) {
    __hip_bfloat16 h = __float2bfloat16(v);
    return *(ushort_t*)&h;
}
__device__ __forceinline__ void split_bf(float v, ushort_t& hi, ushort_t& lo) {
    __hip_bfloat16 h = __float2bfloat16(v);
    hi = *(ushort_t*)&h;
    float hv = __bfloat162float(h);
    __hip_bfloat16 l = __float2bfloat16(v - hv);
    lo = *(ushort_t*)&l;
}

// ---------------------------------------------------------------------------
// ROI helpers — bf16 memory (validated rounds 9-10)
// ---------------------------------------------------------------------------
struct Box {
    float sx, sy, bw, bh, Wf;
    int W;
    const ushort_t* memb;
};

__device__ __forceinline__ void load_box(const float* __restrict__ refr,
                                         const ushort_t* __restrict__ mem16,
                                         int r, int lvl, int lane, Box& bx) {
    const int lvl_hw[4] = {128, 64, 32, 16};
    const int lvl_s[4]  = {0, 16384, 20480, 21504};
    const int b = r / NQ;
    bx.W  = lvl_hw[lvl];
    bx.Wf = (float)bx.W;
    const float* rp = refr + ((size_t)r * NLVL + lvl) * 6;
    float cx = rp[0], cy = rp[1];
    float dl = rp[2], dt = rp[3], dr = rp[4], db = rp[5];
    float x1 = fminf(fmaxf(cx - dl, 0.f), 1.f) * bx.Wf;
    float y1 = fminf(fmaxf(cy - dt, 0.f), 1.f) * bx.Wf;
    float x2 = fminf(fmaxf(cx + dr, 0.f), 1.f) * bx.Wf;
    float y2 = fminf(fmaxf(cy + db, 0.f), 1.f) * bx.Wf;
    bx.sx = x1 - 0.5f;
    bx.sy = y1 - 0.5f;
    bx.bw = (x2 - x1) * (1.f / 7.f);
    bx.bh = (y2 - y1) * (1.f / 7.f);
    bx.memb = mem16 + ((size_t)b * TOTAL + lvl_s[lvl]) * HID + lane * 4;
}

__device__ __forceinline__ void roi_cell(const Box& bx, int cell, float4& out) {
    const int ph = cell / 7, pw = cell % 7;
    float a0 = 0.f, a1 = 0.f, a2 = 0.f, a3 = 0.f;
#pragma unroll
    for (int sub = 0; sub < 4; ++sub) {
        const float tys = (float)ph + ((sub >> 1) + 0.5f) * 0.5f;
        const float txs = (float)pw + ((sub & 1) + 0.5f) * 0.5f;
        float yy = bx.sy + bx.bh * tys;
        float xx = bx.sx + bx.bw * txs;
        if (yy >= -1.f && yy <= bx.Wf && xx >= -1.f && xx <= bx.Wf) {
            float yc = fminf(fmaxf(yy, 0.f), bx.Wf - 1.f);
            float xc = fminf(fmaxf(xx, 0.f), bx.Wf - 1.f);
            float y0f = fminf(floorf(yc), bx.Wf - 2.f);
            float x0f = fminf(floorf(xc), bx.Wf - 2.f);
            float ly = yc - y0f, lx = xc - x0f;
            int y0 = (int)y0f, x0 = (int)x0f;
            const ushort_t* p00 = bx.memb + (size_t)(y0 * bx.W + x0) * HID;
            ushort4 u00 = *(const ushort4*)p00;
            ushort4 u01 = *(const ushort4*)(p00 + HID);
            ushort4 u10 = *(const ushort4*)(p00 + bx.W * HID);
            ushort4 u11 = *(const ushort4*)(p00 + bx.W * HID + HID);
            float w00 = (1.f - ly) * (1.f - lx), w01 = (1.f - ly) * lx;
            float w10 = ly * (1.f - lx), w11 = ly * lx;
            a0 += w00 * bfbits2f(u00.x) + w01 * bfbits2f(u01.x) + w10 * bfbits2f(u10.x) + w11 * bfbits2f(u11.x);
            a1 += w00 * bfbits2f(u00.y) + w01 * bfbits2f(u01.y) + w10 * bfbits2f(u10.y) + w11 * bfbits2f(u11.y);
            a2 += w00 * bfbits2f(u00.z) + w01 * bfbits2f(u01.z) + w10 * bfbits2f(u10.z) + w11 * bfbits2f(u11.z);
            a3 += w00 * bfbits2f(u00.w) + w01 * bfbits2f(u01.w) + w10 * bfbits2f(u10.w) + w11 * bfbits2f(u11.w);
        }
    }
    out.x = a0 * 0.25f; out.y = a1 * 0.25f; out.z = a2 * 0.25f; out.w = a3 * 0.25f;
}

// ---------------------------------------------------------------------------
// Merged prep: esplit(tgt) + 5x tsplit + memory->bf16  (one launch)
// ---------------------------------------------------------------------------
__device__ __forceinline__ void tsplit_body(const float* __restrict__ W,
                                            ushort_t* __restrict__ TH,
                                            ushort_t* __restrict__ TL,
                                            int K, int N, int kb, int nb,
                                            int perm, int tid, float (*sm)[65]) {
    for (int e = tid; e < 64 * 64; e += 256) {
        int kk = e >> 6, nn = e & 63;
        int kp = kb + kk;
        int ks = perm ? ((kp & 63) * 49 + (kp >> 6)) : kp;
        sm[kk][nn] = W[(size_t)ks * N + nb + nn];
    }
    __syncthreads();
    for (int e = tid; e < 64 * 64; e += 256) {
        int nn = e >> 6, kk = e & 63;
        ushort_t h, l;
        split_bf(sm[kk][nn], h, l);
        size_t o = (size_t)(nb + nn) * K + kb + kk;
        TH[o] = h; TL[o] = l;
    }
}

__global__ __launch_bounds__(256) void k_prep(
    const float* __restrict__ tgt, ushort_t* __restrict__ tgtH, ushort_t* __restrict__ tgtL,
    const float* __restrict__ a1w, ushort_t* __restrict__ a1wTH, ushort_t* __restrict__ a1wTL,
    const float* __restrict__ w1, ushort_t* __restrict__ w1TH, ushort_t* __restrict__ w1TL,
    const float* __restrict__ w2, ushort_t* __restrict__ w2TH, ushort_t* __restrict__ w2TL,
    const float* __restrict__ w3, ushort_t* __restrict__ w3TH, ushort_t* __restrict__ w3TL,
    const float* __restrict__ p1w, ushort_t* __restrict__ p1wTH, ushort_t* __restrict__ p1wTL,
    const float* __restrict__ memory, ushort_t* __restrict__ mem16) {
    __shared__ float sm[64][65];
    const int tid = threadIdx.x;
    int b = blockIdx.x;
    if (b < 600) {                       // esplit on tgt (600*256 elems)
        int i = b * 256 + tid;
        ushort_t h, l;
        split_bf(tgt[i], h, l);
        tgtH[i] = h; tgtL[i] = l;
    } else if (b < 728) {                // a1w: K=256 x N=2048
        b -= 600;
        tsplit_body(a1w, a1wTH, a1wTL, 256, 2048, (b % 4) * 64, (b / 4) * 64, 0, tid, sm);
    } else if (b < 924) {                // w1: K=3136 x N=256, PERM
        b -= 728;
        tsplit_body(w1, w1TH, w1TL, 3136, 256, (b % 49) * 64, (b / 49) * 64, 1, tid, sm);
    } else if (b < 956) {                // w2: K=256 x N=512
        b -= 924;
        tsplit_body(w2, w2TH, w2TL, 256, 512, (b % 4) * 64, (b / 4) * 64, 0, tid, sm);
    } else if (b < 1020) {               // w3: K=512 x N=512
        b -= 956;
        tsplit_body(w3, w3TH, w3TL, 512, 512, (b % 8) * 64, (b / 8) * 64, 0, tid, sm);
    } else if (b < 1024) {               // p1w: K=256 x N=64
        b -= 1020;
        tsplit_body(p1w, p1wTH, p1wTL, 256, 64, b * 64, 0, 0, tid, sm);
    } else {                             // memory -> bf16 (10880 blocks)
        b -= 1024;
        size_t i = (size_t)b * 256 + tid;   // float4 index
        float4 v = ((const float4*)memory)[i];
        ushort4 o;
        o.x = f2bfbits(v.x); o.y = f2bfbits(v.y);
        o.z = f2bfbits(v.z); o.w = f2bfbits(v.w);
        ((ushort4*)mem16)[i] = o;
    }
}

// ---------------------------------------------------------------------------
// bf16x3 MFMA GEMM (validated round 4/10). Tile 64x64, 4 waves.
// EPI: 0 = relu -> hi/lo bf16 ; 1 = relu -> fp32 ; 2 = sigmoid -> fp32 ;
//      3 = split-K partial: raw fp32 to Cf + blockIdx.z*M*N (no bias/act)
// AX : 1 = A is exactly bf16 (AL unused; skip lo-term MFMA)
// ---------------------------------------------------------------------------
template <int EPI, int AX>
__global__ __launch_bounds__(256) void k_gmfma(
    const ushort_t* __restrict__ AH, const ushort_t* __restrict__ AL,
    const ushort_t* __restrict__ WH, const ushort_t* __restrict__ WL,
    const float* __restrict__ bias, float* __restrict__ Cf,
    ushort_t* __restrict__ CH, ushort_t* __restrict__ CL,
    int M, int N, int K, int kchunk) {
    __shared__ ushort_t As[AX ? 1 : 2][64][40];
    __shared__ ushort_t Ws[2][64][40];

    const int tid = threadIdx.x;
    const int m0 = blockIdx.x * 64, n0 = blockIdx.y * 64;
    const int wv = tid >> 6, ln = tid & 63;
    const int row = tid >> 2, kc = tid & 3;
    const int gm = min(m0 + row, M - 1);
    const int gn = n0 + row;
    const int arow = wv * 16 + (ln & 15);
    const int koff = (ln >> 4) * 8;

    int kb = 0, ke = K;
    if (EPI == 3) {
        kb = blockIdx.z * kchunk;
        ke = min(K, kb + kchunk);
    }

    floatx4 acc[4];
#pragma unroll
    for (int t = 0; t < 4; ++t) acc[t] = (floatx4){0.f, 0.f, 0.f, 0.f};

    for (int k0 = kb; k0 < ke; k0 += 32) {
        *(uint4*)&As[0][row][kc * 8] = *(const uint4*)(AH + (size_t)gm * K + k0 + kc * 8);
        if constexpr (!AX)
            *(uint4*)&As[AX ? 0 : 1][row][kc * 8] = *(const uint4*)(AL + (size_t)gm * K + k0 + kc * 8);
        *(uint4*)&Ws[0][row][kc * 8] = *(const uint4*)(WH + (size_t)gn * K + k0 + kc * 8);
        *(uint4*)&Ws[1][row][kc * 8] = *(const uint4*)(WL + (size_t)gn * K + k0 + kc * 8);
        __syncthreads();

        short8 aH = *(short8*)&As[0][arow][koff];
        short8 aL = aH;
        if constexpr (!AX) aL = *(short8*)&As[AX ? 0 : 1][arow][koff];
#pragma unroll
        for (int t = 0; t < 4; ++t) {
            short8 wH = *(short8*)&Ws[0][t * 16 + (ln & 15)][koff];
            short8 wL = *(short8*)&Ws[1][t * 16 + (ln & 15)][koff];
            acc[t] = __builtin_amdgcn_mfma_f32_16x16x32_bf16(aH, wH, acc[t], 0, 0, 0);
            acc[t] = __builtin_amdgcn_mfma_f32_16x16x32_bf16(aH, wL, acc[t], 0, 0, 0);
            if constexpr (!AX)
                acc[t] = __builtin_amdgcn_mfma_f32_16x16x32_bf16(aL, wH, acc[t], 0, 0, 0);
        }
        __syncthreads();
    }

    float* Cpart = (EPI == 3) ? Cf + (size_t)blockIdx.z * M * N : Cf;
#pragma unroll
    for (int t = 0; t < 4; ++t) {
        int n = n0 + t * 16 + (ln & 15);
        float bv = (EPI == 3) ? 0.f : bias[n];
#pragma unroll
        for (int reg = 0; reg < 4; ++reg) {
            int m = m0 + wv * 16 + (ln >> 4) * 4 + reg;
            if (m < M) {
                float v = acc[t][reg] + bv;
                if (EPI == 0) {
                    v = fmaxf(v, 0.f);
                    ushort_t h, l;
                    split_bf(v, h, l);
                    CH[(size_t)m * N + n] = h;
                    CL[(size_t)m * N + n] = l;
                } else if (EPI == 1) {
                    Cf[(size_t)m * N + n] = fmaxf(v, 0.f);
                } else if (EPI == 2) {
                    Cf[(size_t)m * N + n] = 1.f / (1.f + expf(-v));
                } else {
                    Cpart[(size_t)m * N + n] = v;
                }
            }
        }
    }
}

// ---------------------------------------------------------------------------
// Split-K reduction for h1: sum 7 partials + bias, relu, hi/lo split.
// grid 600 x 256 threads, one float4 (4 cols) per thread.
// ---------------------------------------------------------------------------
__global__ __launch_bounds__(256) void k_h1red(
    const float* __restrict__ h1p, const float* __restrict__ b1,
    ushort_t* __restrict__ h1H, ushort_t* __restrict__ h1L) {
    const int idx = blockIdx.x * 256 + threadIdx.x;    // float4 index
    const int n = (idx * 4) & 255;
    float4 s = ((const float4*)h1p)[idx];
#pragma unroll
    for (int z = 1; z < 7; ++z) {
        float4 t = ((const float4*)(h1p + (size_t)z * 2400 * 256))[idx];
        s.x += t.x; s.y += t.y; s.z += t.z; s.w += t.w;
    }
    float4 bv = *(const float4*)(b1 + n);
    s.x = fmaxf(s.x + bv.x, 0.f);
    s.y = fmaxf(s.y + bv.y, 0.f);
    s.z = fmaxf(s.z + bv.z, 0.f);
    s.w = fmaxf(s.w + bv.w, 0.f);
    ushort4 H, L;
    split_bf(s.x, H.x, L.x);
    split_bf(s.y, H.y, L.y);
    split_bf(s.z, H.z, L.z);
    split_bf(s.w, H.w, L.w);
    ((ushort4*)h1H)[idx] = H;
    ((ushort4*)h1L)[idx] = L;
}

// ---------------------------------------------------------------------------
// Per instance: ROI-align only -> roi bf16 global. No LDS, no barrier.
// ---------------------------------------------------------------------------
__global__ __launch_bounds__(256) void k_roi(
    const ushort_t* __restrict__ mem16, const float* __restrict__ refr,
    ushort_t* __restrict__ roi) {
    const int tid  = threadIdx.x;
    const int wave = tid >> 6, lane = tid & 63;
    const int lvl = blockIdx.x / 600;
    const int r   = blockIdx.x % 600;
    const int i2  = r * 4 + lvl;

    Box bx;
    load_box(refr, mem16, r, lvl, lane, bx);

    ushort_t* rbase = roi + (size_t)i2 * NCELL * HID;
    for (int cell = wave; cell < NCELL; cell += 4) {
        float4 o;
        roi_cell(bx, cell, o);
        ushort4 pk;
        pk.x = f2bfbits(o.x); pk.y = f2bfbits(o.y);
        pk.z = f2bfbits(o.z); pk.w = f2bfbits(o.w);
        *(ushort4*)&rbase[cell * HID + lane * 4] = pk;
    }
}

// ---------------------------------------------------------------------------
// Fused: per query r: pts = tanh(h3@w4+b4) -> grid_sample*gate -> qe (LDS)
// -> logits -> softmax -> weighted sum -> out.  (validated round 10)
// ---------------------------------------------------------------------------
__global__ __launch_bounds__(256) void k_fuse(
    const ushort_t* __restrict__ roi, const float* __restrict__ h3,
    const float* __restrict__ w4, const float* __restrict__ b4,
    const float* __restrict__ gate, const float* __restrict__ w,
    const float* __restrict__ bias, float* __restrict__ out) {
    __shared__ float sm_qe[32 * HID];
    __shared__ float sm_pts[64];
    __shared__ float sm_hd[32][4];
    __shared__ float sm_l[32];
    __shared__ float sm_e[32];

    const int tid = threadIdx.x;
    const int r = blockIdx.x;

    float* sm_h3 = sm_qe;
    {
        const float4* src = (const float4*)(h3 + (size_t)r * 4 * 512);
        float4* dst = (float4*)sm_h3;
        for (int i = tid; i < 512; i += 256) dst[i] = src[i];
    }
    __syncthreads();

    {
        const int o = tid >> 2, s = tid & 3;
        const int row = o >> 4, col = o & 15;
        float part = 0.f;
        const int kb = s * 128;
        for (int k = kb; k < kb + 128; ++k)
            part += sm_h3[row * 512 + k] * w4[k * 16 + col];
        part += __shfl_down(part, 2);
        part += __shfl_down(part, 1);
        if (s == 0) sm_pts[row * 16 + col] = tanhf(part + b4[col]);
    }
    __syncthreads();

    if (tid < 32) {
        int lvl = tid >> 3, h = tid & 7;
        float gx = sm_pts[lvl * 16 + h * 2];
        float gy = sm_pts[lvl * 16 + h * 2 + 1];
        float ix = ((gx + 1.f) * 7.f - 1.f) * 0.5f;
        float iy = ((gy + 1.f) * 7.f - 1.f) * 0.5f;
        float x0f = floorf(ix), y0f = floorf(iy);
        sm_hd[tid][0] = x0f;
        sm_hd[tid][1] = y0f;
        sm_hd[tid][2] = ix - x0f;
        sm_hd[tid][3] = iy - y0f;
    }
    __syncthreads();

    const float* grow = gate + (size_t)r * 2048;
#pragma unroll
    for (int j = 0; j < 32; ++j) {
        int lvl = j >> 3, h = j & 7;
        const ushort_t* rbase = roi + ((size_t)r * 4 + lvl) * NCELL * HID;
        float x0f = sm_hd[j][0], y0f = sm_hd[j][1];
        float lx = sm_hd[j][2], ly = sm_hd[j][3];
        int x0 = (int)x0f, y0 = (int)y0f;
        float v = 0.f;
#pragma unroll
        for (int dy = 0; dy < 2; ++dy) {
            int yi = y0 + dy;
            if (yi < 0 || yi >= 7) continue;
            float wy = dy ? ly : 1.f - ly;
#pragma unroll
            for (int dx = 0; dx < 2; ++dx) {
                int xi = x0 + dx;
                if (xi < 0 || xi >= 7) continue;
                float wx = dx ? lx : 1.f - lx;
                v += wy * wx * bfbits2f(rbase[(yi * 7 + xi) * HID + tid]);
            }
        }
        sm_qe[j * HID + tid] = v * grow[h * HID + tid];
    }
    __syncthreads();

    const int j = tid >> 3, sub = tid & 7;
    float part = 0.f;
    const int cbase = sub * 32;
    for (int c = 0; c < 32; ++c) part += sm_qe[j * HID + cbase + c] * w[cbase + c];
    part += __shfl_down(part, 4);
    part += __shfl_down(part, 2);
    part += __shfl_down(part, 1);
    if (sub == 0) sm_l[j] = part + bias[0];
    __syncthreads();
    if (tid < 32) {
        float m = -1e30f;
        for (int i = 0; i < 32; ++i) m = fmaxf(m, sm_l[i]);
        sm_e[tid] = expf(sm_l[tid] - m);
    }
    __syncthreads();
    float denom = 0.f;
    for (int i = 0; i < 32; ++i) denom += sm_e[i];
    float inv = 1.f / denom;
    float acc = 0.f;
    for (int jj = 0; jj < 32; ++jj) acc += sm_qe[jj * HID + tid] * sm_e[jj];
    out[(size_t)r * HID + tid] = acc * inv;
}

// ---------------------------------------------------------------------------
extern "C" void kernel_launch(void* const* d_in, const int* in_sizes, int n_in,
                              void* d_out, int out_size, void* d_ws, size_t ws_size,
                              hipStream_t stream) {
    const float* tgt    = (const float*)d_in[0];
    const float* memory = (const float*)d_in[1];
    const float* refr   = (const float*)d_in[2];
    const float* p1w = (const float*)d_in[4];
    const float* p1b = (const float*)d_in[5];
    const float* w1  = (const float*)d_in[6];
    const float* b1  = (const float*)d_in[7];
    const float* w2  = (const float*)d_in[8];
    const float* b2  = (const float*)d_in[9];
    const float* w3  = (const float*)d_in[10];
    const float* b3  = (const float*)d_in[11];
    const float* w4  = (const float*)d_in[12];
    const float* b4  = (const float*)d_in[13];
    const float* a1w = (const float*)d_in[14];
    const float* a1b = (const float*)d_in[15];
    const float* a2w = (const float*)d_in[16];
    const float* a2b = (const float*)d_in[17];
    float* out = (float*)d_out;

    size_t off = 0;
    auto alloc = [&](size_t bytes) {
        void* p = (char*)d_ws + off;
        off += (bytes + 255) & ~(size_t)255;
        return p;
    };
    float*    gate  = (float*)alloc((size_t)600 * 2048 * 4);
    ushort_t* mem16 = (ushort_t*)alloc((size_t)2 * TOTAL * HID * 2);
    ushort_t* roi   = (ushort_t*)alloc((size_t)2400 * NCELL * HID * 2);
    ushort_t* pHb   = (ushort_t*)alloc((size_t)2400 * 3136 * 2);
    ushort_t* pLb   = (ushort_t*)alloc((size_t)2400 * 3136 * 2);
    float*    h1p   = (float*)alloc((size_t)7 * 2400 * 256 * 4);
    ushort_t* h1H   = (ushort_t*)alloc((size_t)2400 * 256 * 2);
    ushort_t* h1L   = (ushort_t*)alloc((size_t)2400 * 256 * 2);
    ushort_t* h2H   = (ushort_t*)alloc((size_t)2400 * 512 * 2);
    ushort_t* h2L   = (ushort_t*)alloc((size_t)2400 * 512 * 2);
    float*    h3    = (float*)alloc((size_t)2400 * 512 * 4);
    ushort_t* tgtH  = (ushort_t*)alloc((size_t)600 * 256 * 2);
    ushort_t* tgtL  = (ushort_t*)alloc((size_t)600 * 256 * 2);
    ushort_t* a1wTH = (ushort_t*)alloc((size_t)2048 * 256 * 2);
    ushort_t* a1wTL = (ushort_t*)alloc((size_t)2048 * 256 * 2);
    ushort_t* w1TH  = (ushort_t*)alloc((size_t)256 * 3136 * 2);
    ushort_t* w1TL  = (ushort_t*)alloc((size_t)256 * 3136 * 2);
    ushort_t* w2TH  = (ushort_t*)alloc((size_t)512 * 256 * 2);
    ushort_t* w2TL  = (ushort_t*)alloc((size_t)512 * 256 * 2);
    ushort_t* w3TH  = (ushort_t*)alloc((size_t)512 * 512 * 2);
    ushort_t* w3TL  = (ushort_t*)alloc((size_t)512 * 512 * 2);
    ushort_t* p1wTH = (ushort_t*)alloc((size_t)64 * 256 * 2);
    ushort_t* p1wTL = (ushort_t*)alloc((size_t)64 * 256 * 2);

    // merged prep: 1024 range blocks + 10880 memory-conversion blocks
    hipLaunchKernelGGL(k_prep, dim3(11904), dim3(256), 0, stream,
                       tgt, tgtH, tgtL, a1w, a1wTH, a1wTL,
                       w1, w1TH, w1TL, w2, w2TH, w2TL, w3, w3TH, w3TL,
                       p1w, p1wTH, p1wTL, memory, mem16);

    // gate = sigmoid(tgt @ a1w + a1b)
    hipLaunchKernelGGL((k_gmfma<2, 0>), dim3(10, 32), dim3(256), 0, stream,
                       tgtH, tgtL, a1wTH, a1wTL, a1b, gate, (ushort_t*)0, (ushort_t*)0,
                       600, 2048, 256, 0);
    // roi (level-major swizzle, bf16 memory, no LDS)
    hipLaunchKernelGGL(k_roi, dim3(2400), dim3(256), 0, stream, mem16, refr, roi);
    // p1 as one batched GEMM: (2400*49 x 256) @ (256 x 64), A exact-bf16
    hipLaunchKernelGGL((k_gmfma<0, 1>), dim3(1838, 1), dim3(256), 0, stream,
                       roi, (ushort_t*)0, p1wTH, p1wTL, p1b, (float*)0, pHb, pLb,
                       2400 * NCELL, 64, 256, 0);
    // w1 GEMM: split-K x7 (kchunk=448) -> partials -> reduce
    hipLaunchKernelGGL((k_gmfma<3, 0>), dim3(38, 4, 7), dim3(256), 0, stream,
                       pHb, pLb, w1TH, w1TL, (float*)0, h1p, (ushort_t*)0, (ushort_t*)0,
                       2400, 256, 3136, 448);
    hipLaunchKernelGGL(k_h1red, dim3(600), dim3(256), 0, stream, h1p, b1, h1H, h1L);
    // w2, w3 GEMMs
    hipLaunchKernelGGL((k_gmfma<0, 0>), dim3(38, 8), dim3(256), 0, stream,
                       h1H, h1L, w2TH, w2TL, b2, (float*)0, h2H, h2L, 2400, 512, 256, 0);
    hipLaunchKernelGGL((k_gmfma<1, 0>), dim3(38, 8), dim3(256), 0, stream,
                       h2H, h2L, w3TH, w3TL, b3, h3, (ushort_t*)0, (ushort_t*)0,
                       2400, 512, 512, 0);
    // fused l4 + sample + softmax-output
    hipLaunchKernelGGL(k_fuse, dim3(600), dim3(256), 0, stream,
                       roi, h3, w4, b4, gate, a2w, a2b, out);
}